// Round 4
// baseline (816.729 us; speedup 1.0000x reference)
//
#include <hip/hip_runtime.h>

#define Bv 32
#define Sv 128
#define Tv 2000
#define Dv 768
#define Hv 256
#define Rv 50

// ---------------------------------------------------------------------------
// Kernel 1: batch-streaming audio segment mean.
// grid = 32 batches x 8 dim-groups (96 dims each) = 256 blocks, 256 threads.
// Phase 1: per-frame 128-bit token membership mask (LDS, atomicOr).
// Phase 2: stream 2000 frames once (reg double-buffered 32-frame tiles),
//          ds_add_f32 scatter into LDS acc[128][100] (padded rows).
// Phase 3: scale by 1/count (or 0) and store.
// Dim rotation ((s+f)&7)*12 decorrelates same-address atomic collisions.
// ---------------------------------------------------------------------------
__global__ __launch_bounds__(256) void seg_mean_batch(
    const float* __restrict__ audio, const float* __restrict__ st,
    const float* __restrict__ et, float* __restrict__ smean)
{
  const int b = blockIdx.x >> 3;
  const int g = blockIdx.x & 7;
  const int tid = threadIdx.x;
  const int f = tid >> 3;              // frame slot 0..31
  const int s = tid & 7;
  const int d0 = ((s + f) & 7) * 12;   // rotated 12-dim chunk within 96

  extern __shared__ float sdyn[];
  float* sacc = sdyn;                         // 128*100 floats
  unsigned* smask = (unsigned*)(sdyn + 12800); // 2000*4 u32
  float* sscale = (float*)(smask + 8000);      // 128 floats

  // zero acc + mask
  {
    float4* a4 = (float4*)sacc;
    for (int i = tid; i < 3200; i += 256) a4[i] = float4{0, 0, 0, 0};
    uint4* m4 = (uint4*)smask;
    for (int i = tid; i < 2000; i += 256) m4[i] = uint4{0, 0, 0, 0};
  }
  __syncthreads();

  // phase 1: interval masks + scale
  if (tid < 128) {
    const int tok = b * Sv + tid;
    const float stime = st[tok], etime = et[tok];
    const int si = (int)(stime * 50.0f);   // trunc == floor for >= 0
    const int ei = (int)(etime * 50.0f);
    const bool valid = (ei > si) && (ei <= Tv);
    const int sc = min(max(si, 0), Tv);
    const int ec = min(max(ei, 0), Tv);
    sscale[tid] = valid ? (1.0f / (float)max(ec - sc, 1)) : 0.0f;
    const unsigned bit = 1u << (tid & 31);
    const int w = tid >> 5;
    for (int t = sc; t < ec; ++t)
      atomicOr(&smask[t * 4 + w], bit);
  }
  __syncthreads();

  // phase 2: stream frames, scatter-add (no barriers: atomics only)
  const float* abase = audio + (size_t)b * Tv * Dv + g * 96 + d0;

#define LOADT(R0, R1, R2, T0)                                        \
  {                                                                   \
    const int t_ = (T0) + f;                                          \
    if (t_ < Tv) {                                                    \
      const float4* p_ = (const float4*)(abase + (size_t)t_ * Dv);    \
      R0 = p_[0]; R1 = p_[1]; R2 = p_[2];                             \
    } else {                                                          \
      R0 = R1 = R2 = float4{0, 0, 0, 0};                              \
    }                                                                 \
  }

#define PROC(R0, R1, R2, T0)                                          \
  {                                                                   \
    const int t_ = (T0) + f;                                          \
    if (t_ < Tv) {                                                    \
      const uint4 mk_ = *(const uint4*)&smask[t_ * 4];                \
      const unsigned mw_[4] = {mk_.x, mk_.y, mk_.z, mk_.w};           \
      _Pragma("unroll")                                               \
      for (int w_ = 0; w_ < 4; ++w_) {                                \
        unsigned m_ = mw_[w_];                                        \
        while (m_) {                                                  \
          const int i_ = (w_ << 5) + __ffs(m_) - 1;                   \
          m_ &= m_ - 1;                                               \
          float* ap_ = &sacc[i_ * 100 + d0];                          \
          atomicAdd(ap_ + 0, R0.x);  atomicAdd(ap_ + 1, R0.y);        \
          atomicAdd(ap_ + 2, R0.z);  atomicAdd(ap_ + 3, R0.w);        \
          atomicAdd(ap_ + 4, R1.x);  atomicAdd(ap_ + 5, R1.y);        \
          atomicAdd(ap_ + 6, R1.z);  atomicAdd(ap_ + 7, R1.w);        \
          atomicAdd(ap_ + 8, R2.x);  atomicAdd(ap_ + 9, R2.y);        \
          atomicAdd(ap_ + 10, R2.z); atomicAdd(ap_ + 11, R2.w);       \
        }                                                             \
      }                                                               \
    }                                                                 \
  }

  float4 A0, A1, A2, B0, B1, B2;
  LOADT(A0, A1, A2, 0);
  for (int t0 = 0; t0 < Tv; t0 += 64) {
    LOADT(B0, B1, B2, t0 + 32);
    PROC(A0, A1, A2, t0);
    LOADT(A0, A1, A2, t0 + 64);
    PROC(B0, B1, B2, t0 + 32);
  }
#undef LOADT
#undef PROC

  __syncthreads();

  // phase 3: scale + store
  float* orow = smean + (size_t)(b * Sv) * Dv + g * 96;
  for (int idx = tid; idx < 128 * 96; idx += 256) {
    const int i = idx / 96;
    const int d = idx - i * 96;
    orow[(size_t)i * Dv + d] = sacc[i * 100 + d] * sscale[i];
  }
}

// ---------------------------------------------------------------------------
// Prep: wpad (mlp1_w padded K 250->256) + word/pos gathers + x0 zero tail.
// blocks [0,256): wpad. blocks [256,768): 8 tokens each.
// ---------------------------------------------------------------------------
__global__ __launch_bounds__(256) void prep(
    const int* __restrict__ words, const int* __restrict__ pos_ids,
    const float* __restrict__ word_W, const float* __restrict__ pos_W,
    const float* __restrict__ m1w, float* __restrict__ wpad,
    float* __restrict__ x0)
{
  const int tid = threadIdx.x;
  if (blockIdx.x < 256) {
    const int idx = blockIdx.x * 256 + tid;
    const int r = idx >> 8, c = idx & 255;
    wpad[idx] = (c < 250) ? m1w[r * 250 + c] : 0.0f;
  } else {
    const int base = (blockIdx.x - 256) * 8;
#pragma unroll
    for (int rep = 0; rep < 8; ++rep) {
      const int tok = base + rep;
      if (tid < 100) {
        x0[(size_t)tok * 256 + tid] = word_W[(size_t)words[tok] * 100 + tid];
      } else if (tid < 150) {
        x0[(size_t)tok * 256 + tid] = pos_W[pos_ids[tok] * 50 + (tid - 100)];
      } else if (tid >= 250) {
        x0[(size_t)tok * 256 + tid] = 0.0f;
      }
    }
  }
}

// ---------------------------------------------------------------------------
// GEMM core: 32x64 tile, 256 threads, 2x4 acc/thread, reg-prefetch K-chunks.
// C[row0..row0+32, n0..n0+64] = A[M,K] @ W[N,K]^T (+bias, +relu), col guard N.
// ---------------------------------------------------------------------------
template<bool BIAS, bool RELU>
__device__ __forceinline__ void gemm_core(
    const float* __restrict__ A, int lda,
    const float* __restrict__ W, int ldw,
    const float* __restrict__ bias,
    float* __restrict__ C, int ldc, int c0,
    int N, int K, int row0, int n0)
{
  __shared__ float sA[16][34];
  __shared__ float sB[16][68];

  const int tid = threadIdx.x;
  const int tm = tid >> 4;          // 0..15 -> rows 2tm,2tm+1
  const int tn = tid & 15;          // 0..15 -> cols 4tn..4tn+3

  float acc[2][4] = {};

  const int rowA = tid >> 2;        // 0..63 (A uses <32)
  const int kq = (tid & 3) << 2;    // 0,4,8,12
  const bool aact = tid < 128;
  const bool wval = (n0 + rowA) < N;

  const float* Ap = A + (size_t)(row0 + (rowA & 31)) * lda + kq;
  const float* Wp = W + (size_t)(wval ? (n0 + rowA) : 0) * ldw + kq;

  float4 av = float4{0, 0, 0, 0}, bv = float4{0, 0, 0, 0};
  if (aact) av = *(const float4*)Ap;
  if (wval) bv = *(const float4*)Wp;

  int k0 = 0;
  while (true) {
    __syncthreads();
    if (aact) {
      sA[kq + 0][rowA] = av.x; sA[kq + 1][rowA] = av.y;
      sA[kq + 2][rowA] = av.z; sA[kq + 3][rowA] = av.w;
    }
    sB[kq + 0][rowA] = bv.x; sB[kq + 1][rowA] = bv.y;
    sB[kq + 2][rowA] = bv.z; sB[kq + 3][rowA] = bv.w;
    __syncthreads();

    const int kn = k0 + 16;
    const bool more = kn < K;
    if (more) {
      if (aact) av = *(const float4*)(Ap + kn);
      if (wval) bv = *(const float4*)(Wp + kn);
    }

#pragma unroll
    for (int kk = 0; kk < 16; ++kk) {
      const float2 a = *(const float2*)&sA[kk][tm * 2];
      const float4 b = *(const float4*)&sB[kk][tn * 4];
      acc[0][0] += a.x * b.x; acc[0][1] += a.x * b.y;
      acc[0][2] += a.x * b.z; acc[0][3] += a.x * b.w;
      acc[1][0] += a.y * b.x; acc[1][1] += a.y * b.y;
      acc[1][2] += a.y * b.z; acc[1][3] += a.y * b.w;
    }

    if (!more) break;
    k0 = kn;
  }

#pragma unroll
  for (int i = 0; i < 2; ++i) {
    const int row = row0 + tm * 2 + i;
    float* crow = C + (size_t)row * ldc + c0;
#pragma unroll
    for (int j = 0; j < 4; ++j) {
      const int col = n0 + tn * 4 + j;
      if (col < N) {
        float v = acc[i][j];
        if (BIAS) v += bias[col];
        if (RELU) v = fmaxf(v, 0.0f);
        crow[col] = v;
      }
    }
  }
}

template<bool BIAS, bool RELU>
__global__ __launch_bounds__(256) void gemm_tn(
    const float* __restrict__ A, int lda,
    const float* __restrict__ W, int ldw,
    const float* __restrict__ bias,
    float* __restrict__ C, int ldc, int c0,
    int N, int K)
{
  gemm_core<BIAS, RELU>(A, lda, W, ldw, bias, C, ldc, c0, N, K,
                        blockIdx.x * 32, blockIdx.y * 64);
}

// rel projections: y=0 -> relh = head @ rw[:, :256]^T + rb
//                  y=1 -> reld = xfeat @ rw[:, 256:]^T
__global__ __launch_bounds__(256) void rel_gemm(
    const float* __restrict__ head, const float* __restrict__ xfeat,
    const float* __restrict__ rw, const float* __restrict__ rb,
    float* __restrict__ relh, float* __restrict__ reld)
{
  if (blockIdx.y == 0)
    gemm_core<true, false>(head, 256, rw, 512, rb, relh, 50, 0,
                           50, 256, blockIdx.x * 32, 0);
  else
    gemm_core<false, false>(xfeat, 256, rw + 256, 512, nullptr, reld, 50, 0,
                            50, 256, blockIdx.x * 32, 0);
}

// ---------------------------------------------------------------------------
// Fused scores kernel.
//  blocks [0, 512):  arc_scores 32x32 tiles
//  blocks [512, 4608): rel broadcast-add
// ---------------------------------------------------------------------------
__global__ __launch_bounds__(256) void fused_scores(
    const float* __restrict__ head, const float* __restrict__ dep,
    const float* __restrict__ relh, const float* __restrict__ reld,
    float* __restrict__ arc_out, float* __restrict__ rel_out)
{
  __shared__ float smem[6450];
  const int tid = threadIdx.x;

  if (blockIdx.x < 512) {
    const int blk = blockIdx.x;
    const int b = blk >> 4;
    const int tile = blk & 15;
    const int i0 = (tile >> 2) * 32;
    const int j0 = (tile & 3) * 32;

    float (*sh)[33] = (float(*)[33])smem;
    float (*sd)[33] = (float(*)[33])(smem + 1056);

    const int r = tid >> 3;
    const int c = (tid & 7) << 2;
    const int ty = tid >> 4;
    const int tx = tid & 15;

    float acc00 = 0.f, acc01 = 0.f, acc10 = 0.f, acc11 = 0.f;
    const float* hb = head + (size_t)(b * Sv + i0) * Hv;
    const float* db = dep + (size_t)(b * Sv + j0) * Hv;

    for (int k0 = 0; k0 < Hv; k0 += 32) {
      float4 hv = *(const float4*)(hb + (size_t)r * Hv + k0 + c);
      float4 dv = *(const float4*)(db + (size_t)r * Hv + k0 + c);
      __syncthreads();
      sh[r][c] = hv.x; sh[r][c+1] = hv.y; sh[r][c+2] = hv.z; sh[r][c+3] = hv.w;
      sd[r][c] = dv.x; sd[r][c+1] = dv.y; sd[r][c+2] = dv.z; sd[r][c+3] = dv.w;
      __syncthreads();
#pragma unroll
      for (int kk = 0; kk < 32; ++kk) {
        float h0 = sh[ty][kk],  h1 = sh[ty + 16][kk];
        float d0 = sd[tx][kk],  d1 = sd[tx + 16][kk];
        acc00 += h0 * d0; acc01 += h0 * d1;
        acc10 += h1 * d0; acc11 += h1 * d1;
      }
    }

    float* ob = arc_out + (size_t)b * Sv * Sv;
    ob[(i0 + ty) * Sv + j0 + tx]           = acc00;
    ob[(i0 + ty) * Sv + j0 + tx + 16]      = acc01;
    ob[(i0 + ty + 16) * Sv + j0 + tx]      = acc10;
    ob[(i0 + ty + 16) * Sv + j0 + tx + 16] = acc11;
  } else {
    const int bi = blockIdx.x - 512;
    const int b = bi >> 7;

    float* srd = smem;
    float* shi = smem + 6400;

    const float4* rd4 = (const float4*)(reld + (size_t)b * Sv * Rv);
    float4* s4 = (float4*)srd;
    for (int n = tid; n < (Sv * Rv / 4); n += 256) s4[n] = rd4[n];
    if (tid < Rv) shi[tid] = relh[(size_t)bi * Rv + tid];
    __syncthreads();

    float2* out2 = (float2*)(rel_out + (size_t)bi * Sv * Rv);
    for (int n = tid; n < (Sv * Rv / 2); n += 256) {
      const int j = n / 25;
      const int r = (n - j * 25) * 2;
      const float* rdj = srd + j * Rv;
      float2 v;
      v.x = shi[r]     + rdj[r];
      v.y = shi[r + 1] + rdj[r + 1];
      out2[n] = v;
    }
  }
}

// ---------------------------------------------------------------------------
extern "C" void kernel_launch(void* const* d_in, const int* in_sizes, int n_in,
                              void* d_out, int out_size, void* d_ws, size_t ws_size,
                              hipStream_t stream) {
  const int*   words   = (const int*)d_in[0];
  const int*   pos_ids = (const int*)d_in[1];
  const float* audio   = (const float*)d_in[2];
  const float* st      = (const float*)d_in[3];
  const float* et      = (const float*)d_in[4];
  const float* word_W  = (const float*)d_in[5];
  const float* pos_W   = (const float*)d_in[6];
  const float* audio_w = (const float*)d_in[7];
  const float* audio_b = (const float*)d_in[8];
  const float* m1w     = (const float*)d_in[9];
  const float* m1b     = (const float*)d_in[10];
  const float* m2w     = (const float*)d_in[11];
  const float* m2b     = (const float*)d_in[12];
  const float* aw      = (const float*)d_in[13];
  const float* ab      = (const float*)d_in[14];
  const float* rw      = (const float*)d_in[15];
  const float* rb      = (const float*)d_in[16];

  float* out = (float*)d_out;
  float* ws = (float*)d_ws;

  const size_t NT = (size_t)Bv * Sv;            // 4096 tokens
  float* smean = ws;                            // NT*768
  float* x0    = smean + NT * Dv;               // NT*256
  float* h1    = x0    + NT * 256;              // NT*256
  float* xfeat = h1    + NT * 256;              // NT*256 (dep)
  float* head  = xfeat + NT * 256;              // NT*256
  float* relh  = head  + NT * 256;              // NT*50
  float* reld  = relh  + NT * Rv;               // NT*50
  float* wpad  = reld  + NT * Rv;               // 256*256

  const int lds_bytes = (12800 + 8000 + 128) * 4;  // 83712 B
  seg_mean_batch<<<256, 256, lds_bytes, stream>>>(audio, st, et, smean);

  prep<<<768, 256, 0, stream>>>(words, pos_ids, word_W, pos_W, m1w, wpad, x0);

  // audio projection: x0[:, 150:250] = smean @ audio_w.T + audio_b
  gemm_tn<true, false><<<dim3(128, 2), 256, 0, stream>>>(
      smean, Dv, audio_w, Dv, audio_b, x0, 256, 150, 100, Dv);

  // mlp1: h1 = relu(x0 @ wpad.T + m1b)
  gemm_tn<true, true><<<dim3(128, 4), 256, 0, stream>>>(
      x0, 256, wpad, 256, m1b, h1, 256, 0, 256, 256);

  // mlp2: xfeat = relu(h1 @ m2w.T + m2b)
  gemm_tn<true, true><<<dim3(128, 4), 256, 0, stream>>>(
      h1, 256, m2w, 256, m2b, xfeat, 256, 0, 256, 256);

  // arc head: head = xfeat @ aw.T + ab
  gemm_tn<true, false><<<dim3(128, 4), 256, 0, stream>>>(
      xfeat, 256, aw, 256, ab, head, 256, 0, 256, 256);

  // rel projections (merged)
  rel_gemm<<<dim3(128, 2), 256, 0, stream>>>(head, xfeat, rw, rb, relh, reld);

  fused_scores<<<512 + (int)NT, 256, 0, stream>>>(
      head, xfeat, relh, reld, out, out + (size_t)Bv * Sv * Sv);
}

// Round 5
// 204.758 us; speedup vs baseline: 3.9888x; 3.9888x over previous
//
#include <hip/hip_runtime.h>

#define Bv 32
#define Sv 128
#define Tv 2000
#define Dv 768
#define Hv 256
#define Rv 50
#define CHF 16            // frames per chunk
#define NCH 125           // chunks per batch (125*16 = 2000)
#define CSTRIDE 128       // csc chunk stride (entries 0..125 used)

// ---------------------------------------------------------------------------
// stage1: blocks [0,4000): 16-frame chunk sums (audio streamed exactly once)
//         blocks [4000,4256): wpad (mlp1_w K padded 250->256)
//         blocks [4256,4768): word/pos gathers into x0 (8 tokens/block)
// ---------------------------------------------------------------------------
__global__ __launch_bounds__(256) void stage1(
    const float* __restrict__ audio, const int* __restrict__ words,
    const int* __restrict__ pos_ids, const float* __restrict__ word_W,
    const float* __restrict__ pos_W, const float* __restrict__ m1w,
    float* __restrict__ chunkSum, float* __restrict__ wpad,
    float* __restrict__ x0)
{
  const int tid = threadIdx.x;
  const int blk = blockIdx.x;

  if (blk < Bv * NCH) {
    const int b = blk / NCH;
    const int c = blk - b * NCH;
    const float* base = audio + ((size_t)b * Tv + c * CHF) * Dv;
    float s0 = 0.f, s1 = 0.f, s2 = 0.f;
#pragma unroll
    for (int f = 0; f < CHF; ++f) {
      const float* row = base + (size_t)f * Dv;
      s0 += row[tid];
      s1 += row[tid + 256];
      s2 += row[tid + 512];
    }
    float* o = chunkSum + (size_t)blk * Dv;
    o[tid] = s0; o[tid + 256] = s1; o[tid + 512] = s2;
  } else if (blk < Bv * NCH + 256) {
    const int idx = (blk - Bv * NCH) * 256 + tid;
    const int r = idx >> 8, cc = idx & 255;
    wpad[idx] = (cc < 250) ? m1w[r * 250 + cc] : 0.0f;
  } else {
    const int base = (blk - Bv * NCH - 256) * 8;
#pragma unroll
    for (int rep = 0; rep < 8; ++rep) {
      const int tok = base + rep;
      if (tid < 100) {
        x0[(size_t)tok * 256 + tid] = word_W[(size_t)words[tok] * 100 + tid];
      } else if (tid < 150) {
        x0[(size_t)tok * 256 + tid] = pos_W[pos_ids[tok] * 50 + (tid - 100)];
      } else if (tid >= 250) {
        x0[(size_t)tok * 256 + tid] = 0.0f;
      }
    }
  }
}

// ---------------------------------------------------------------------------
// scan: exclusive prefix over 125 chunk sums per batch. grid=32, block=768.
// ---------------------------------------------------------------------------
__global__ __launch_bounds__(768) void scan_chunks(
    const float* __restrict__ chunkSum, float* __restrict__ csc)
{
  const int b = blockIdx.x;
  const int d = threadIdx.x;
  const float* in = chunkSum + (size_t)b * NCH * Dv + d;
  float* out = csc + (size_t)b * CSTRIDE * Dv + d;

  float run = 0.f;
  for (int c0 = 0; c0 < NCH; c0 += 5) {      // 125 = 25 x 5
    float v0 = in[(size_t)(c0 + 0) * Dv];
    float v1 = in[(size_t)(c0 + 1) * Dv];
    float v2 = in[(size_t)(c0 + 2) * Dv];
    float v3 = in[(size_t)(c0 + 3) * Dv];
    float v4 = in[(size_t)(c0 + 4) * Dv];
    out[(size_t)(c0 + 0) * Dv] = run; run += v0;
    out[(size_t)(c0 + 1) * Dv] = run; run += v1;
    out[(size_t)(c0 + 2) * Dv] = run; run += v2;
    out[(size_t)(c0 + 3) * Dv] = run; run += v3;
    out[(size_t)(c0 + 4) * Dv] = run; run += v4;
  }
  out[(size_t)NCH * Dv] = run;
}

// ---------------------------------------------------------------------------
// seg_final: per token, seg = csc[cE]-csc[cS] + partial_e - partial_s, scaled.
// grid = 4096 tokens, block = 256 (3 dims/thread). All loads independent.
// ---------------------------------------------------------------------------
__global__ __launch_bounds__(256) void seg_final(
    const float* __restrict__ audio, const float* __restrict__ csc,
    const float* __restrict__ st, const float* __restrict__ et,
    float* __restrict__ smean)
{
  const int tok = blockIdx.x;
  const int b = tok >> 7;
  const int tid = threadIdx.x;

  const float stime = st[tok], etime = et[tok];
  const int si = (int)(stime * 50.0f);   // trunc == floor for >= 0
  const int ei = (int)(etime * 50.0f);
  const bool valid = (ei > si) && (ei <= Tv);
  const int sc = min(max(si, 0), Tv);
  const int ec = min(max(ei, 0), Tv);
  const float m = valid ? (1.0f / (float)max(ec - sc, 1)) : 0.0f;

  const int cS = sc >> 4, pS = sc & 15;
  const int cE = ec >> 4, pE = ec & 15;

  const float* cscb = csc + (size_t)b * CSTRIDE * Dv;
  const float* ab = audio + (size_t)b * Tv * Dv;

  const float* pe_ = cscb + (size_t)cE * Dv;
  const float* ps_ = cscb + (size_t)cS * Dv;
  float acc0 = pe_[tid]       - ps_[tid];
  float acc1 = pe_[tid + 256] - ps_[tid + 256];
  float acc2 = pe_[tid + 512] - ps_[tid + 512];

  for (int f = 0; f < pE; ++f) {
    const float* row = ab + (size_t)(cE * CHF + f) * Dv;
    acc0 += row[tid]; acc1 += row[tid + 256]; acc2 += row[tid + 512];
  }
  for (int f = 0; f < pS; ++f) {
    const float* row = ab + (size_t)(cS * CHF + f) * Dv;
    acc0 -= row[tid]; acc1 -= row[tid + 256]; acc2 -= row[tid + 512];
  }

  float* o = smean + (size_t)tok * Dv;
  o[tid] = acc0 * m; o[tid + 256] = acc1 * m; o[tid + 512] = acc2 * m;
}

// ---------------------------------------------------------------------------
// GEMM core: 32x64 tile, 256 threads, 2x4 acc/thread, reg-prefetch K-chunks.
// ---------------------------------------------------------------------------
template<bool BIAS, bool RELU>
__device__ __forceinline__ void gemm_core(
    const float* __restrict__ A, int lda,
    const float* __restrict__ W, int ldw,
    const float* __restrict__ bias,
    float* __restrict__ C, int ldc, int c0,
    int N, int K, int row0, int n0)
{
  __shared__ float sA[16][34];
  __shared__ float sB[16][68];

  const int tid = threadIdx.x;
  const int tm = tid >> 4;
  const int tn = tid & 15;

  float acc[2][4] = {};

  const int rowA = tid >> 2;
  const int kq = (tid & 3) << 2;
  const bool aact = tid < 128;
  const bool wval = (n0 + rowA) < N;

  const float* Ap = A + (size_t)(row0 + (rowA & 31)) * lda + kq;
  const float* Wp = W + (size_t)(wval ? (n0 + rowA) : 0) * ldw + kq;

  float4 av = float4{0, 0, 0, 0}, bv = float4{0, 0, 0, 0};
  if (aact) av = *(const float4*)Ap;
  if (wval) bv = *(const float4*)Wp;

  int k0 = 0;
  while (true) {
    __syncthreads();
    if (aact) {
      sA[kq + 0][rowA] = av.x; sA[kq + 1][rowA] = av.y;
      sA[kq + 2][rowA] = av.z; sA[kq + 3][rowA] = av.w;
    }
    sB[kq + 0][rowA] = bv.x; sB[kq + 1][rowA] = bv.y;
    sB[kq + 2][rowA] = bv.z; sB[kq + 3][rowA] = bv.w;
    __syncthreads();

    const int kn = k0 + 16;
    const bool more = kn < K;
    if (more) {
      if (aact) av = *(const float4*)(Ap + kn);
      if (wval) bv = *(const float4*)(Wp + kn);
    }

#pragma unroll
    for (int kk = 0; kk < 16; ++kk) {
      const float2 a = *(const float2*)&sA[kk][tm * 2];
      const float4 b = *(const float4*)&sB[kk][tn * 4];
      acc[0][0] += a.x * b.x; acc[0][1] += a.x * b.y;
      acc[0][2] += a.x * b.z; acc[0][3] += a.x * b.w;
      acc[1][0] += a.y * b.x; acc[1][1] += a.y * b.y;
      acc[1][2] += a.y * b.z; acc[1][3] += a.y * b.w;
    }

    if (!more) break;
    k0 = kn;
  }

#pragma unroll
  for (int i = 0; i < 2; ++i) {
    const int row = row0 + tm * 2 + i;
    float* crow = C + (size_t)row * ldc + c0;
#pragma unroll
    for (int j = 0; j < 4; ++j) {
      const int col = n0 + tn * 4 + j;
      if (col < N) {
        float v = acc[i][j];
        if (BIAS) v += bias[col];
        if (RELU) v = fmaxf(v, 0.0f);
        crow[col] = v;
      }
    }
  }
}

template<bool BIAS, bool RELU>
__global__ __launch_bounds__(256) void gemm_tn(
    const float* __restrict__ A, int lda,
    const float* __restrict__ W, int ldw,
    const float* __restrict__ bias,
    float* __restrict__ C, int ldc, int c0,
    int N, int K)
{
  gemm_core<BIAS, RELU>(A, lda, W, ldw, bias, C, ldc, c0, N, K,
                        blockIdx.x * 32, blockIdx.y * 64);
}

__global__ __launch_bounds__(256) void rel_gemm(
    const float* __restrict__ head, const float* __restrict__ xfeat,
    const float* __restrict__ rw, const float* __restrict__ rb,
    float* __restrict__ relh, float* __restrict__ reld)
{
  if (blockIdx.y == 0)
    gemm_core<true, false>(head, 256, rw, 512, rb, relh, 50, 0,
                           50, 256, blockIdx.x * 32, 0);
  else
    gemm_core<false, false>(xfeat, 256, rw + 256, 512, nullptr, reld, 50, 0,
                            50, 256, blockIdx.x * 32, 0);
}

// ---------------------------------------------------------------------------
// Fused scores: blocks [0,512) arc 32x32 tiles; [512,4608) rel broadcast-add.
// ---------------------------------------------------------------------------
__global__ __launch_bounds__(256) void fused_scores(
    const float* __restrict__ head, const float* __restrict__ dep,
    const float* __restrict__ relh, const float* __restrict__ reld,
    float* __restrict__ arc_out, float* __restrict__ rel_out)
{
  __shared__ float smem[6450];
  const int tid = threadIdx.x;

  if (blockIdx.x < 512) {
    const int blk = blockIdx.x;
    const int b = blk >> 4;
    const int tile = blk & 15;
    const int i0 = (tile >> 2) * 32;
    const int j0 = (tile & 3) * 32;

    float (*sh)[33] = (float(*)[33])smem;
    float (*sd)[33] = (float(*)[33])(smem + 1056);

    const int r = tid >> 3;
    const int c = (tid & 7) << 2;
    const int ty = tid >> 4;
    const int tx = tid & 15;

    float acc00 = 0.f, acc01 = 0.f, acc10 = 0.f, acc11 = 0.f;
    const float* hb = head + (size_t)(b * Sv + i0) * Hv;
    const float* db = dep + (size_t)(b * Sv + j0) * Hv;

    for (int k0 = 0; k0 < Hv; k0 += 32) {
      float4 hv = *(const float4*)(hb + (size_t)r * Hv + k0 + c);
      float4 dv = *(const float4*)(db + (size_t)r * Hv + k0 + c);
      __syncthreads();
      sh[r][c] = hv.x; sh[r][c+1] = hv.y; sh[r][c+2] = hv.z; sh[r][c+3] = hv.w;
      sd[r][c] = dv.x; sd[r][c+1] = dv.y; sd[r][c+2] = dv.z; sd[r][c+3] = dv.w;
      __syncthreads();
#pragma unroll
      for (int kk = 0; kk < 32; ++kk) {
        float h0 = sh[ty][kk],  h1 = sh[ty + 16][kk];
        float d0 = sd[tx][kk],  d1 = sd[tx + 16][kk];
        acc00 += h0 * d0; acc01 += h0 * d1;
        acc10 += h1 * d0; acc11 += h1 * d1;
      }
    }

    float* ob = arc_out + (size_t)b * Sv * Sv;
    ob[(i0 + ty) * Sv + j0 + tx]           = acc00;
    ob[(i0 + ty) * Sv + j0 + tx + 16]      = acc01;
    ob[(i0 + ty + 16) * Sv + j0 + tx]      = acc10;
    ob[(i0 + ty + 16) * Sv + j0 + tx + 16] = acc11;
  } else {
    const int bi = blockIdx.x - 512;
    const int b = bi >> 7;

    float* srd = smem;
    float* shi = smem + 6400;

    const float4* rd4 = (const float4*)(reld + (size_t)b * Sv * Rv);
    float4* s4 = (float4*)srd;
    for (int n = tid; n < (Sv * Rv / 4); n += 256) s4[n] = rd4[n];
    if (tid < Rv) shi[tid] = relh[(size_t)bi * Rv + tid];
    __syncthreads();

    float2* out2 = (float2*)(rel_out + (size_t)bi * Sv * Rv);
    for (int n = tid; n < (Sv * Rv / 2); n += 256) {
      const int j = n / 25;
      const int r = (n - j * 25) * 2;
      const float* rdj = srd + j * Rv;
      float2 v;
      v.x = shi[r]     + rdj[r];
      v.y = shi[r + 1] + rdj[r + 1];
      out2[n] = v;
    }
  }
}

// ---------------------------------------------------------------------------
extern "C" void kernel_launch(void* const* d_in, const int* in_sizes, int n_in,
                              void* d_out, int out_size, void* d_ws, size_t ws_size,
                              hipStream_t stream) {
  const int*   words   = (const int*)d_in[0];
  const int*   pos_ids = (const int*)d_in[1];
  const float* audio   = (const float*)d_in[2];
  const float* st      = (const float*)d_in[3];
  const float* et      = (const float*)d_in[4];
  const float* word_W  = (const float*)d_in[5];
  const float* pos_W   = (const float*)d_in[6];
  const float* audio_w = (const float*)d_in[7];
  const float* audio_b = (const float*)d_in[8];
  const float* m1w     = (const float*)d_in[9];
  const float* m1b     = (const float*)d_in[10];
  const float* m2w     = (const float*)d_in[11];
  const float* m2b     = (const float*)d_in[12];
  const float* aw      = (const float*)d_in[13];
  const float* ab      = (const float*)d_in[14];
  const float* rw      = (const float*)d_in[15];
  const float* rb      = (const float*)d_in[16];

  float* out = (float*)d_out;
  float* ws = (float*)d_ws;

  const size_t NT = (size_t)Bv * Sv;            // 4096 tokens
  // Overlaid workspace (31.3 MB total, same footprint as round 3):
  //   ws0: chunkSum [32*125*768 = 3.072M] then smean [NT*768 = 3.146M]
  //        (chunkSum dead after scan, before smean is written)
  //   csc: overlays h1+xfeat+head [3*NT*256 = 3.146M = 32*128*768 exactly]
  //        (csc dead after seg_final, before mlp1 writes h1)
  float* smean    = ws;                          // & chunkSum
  float* chunkSum = ws;
  float* x0    = smean + NT * Dv;                // NT*256
  float* h1    = x0    + NT * 256;               // NT*256
  float* xfeat = h1    + NT * 256;               // NT*256 (dep)
  float* head  = xfeat + NT * 256;               // NT*256
  float* csc   = h1;                             // 32*128*768 overlay
  float* relh  = head  + NT * 256;               // NT*50
  float* reld  = relh  + NT * Rv;                // NT*50
  float* wpad  = reld  + NT * Rv;                // 256*256

  stage1<<<Bv * NCH + 256 + 512, 256, 0, stream>>>(
      audio, words, pos_ids, word_W, pos_W, m1w, chunkSum, wpad, x0);

  scan_chunks<<<Bv, 768, 0, stream>>>(chunkSum, csc);

  seg_final<<<(int)NT, 256, 0, stream>>>(audio, csc, st, et, smean);

  // audio projection: x0[:, 150:250] = smean @ audio_w.T + audio_b
  gemm_tn<true, false><<<dim3(128, 2), 256, 0, stream>>>(
      smean, Dv, audio_w, Dv, audio_b, x0, 256, 150, 100, Dv);

  // mlp1: h1 = relu(x0 @ wpad.T + m1b)
  gemm_tn<true, true><<<dim3(128, 4), 256, 0, stream>>>(
      x0, 256, wpad, 256, m1b, h1, 256, 0, 256, 256);

  // mlp2: xfeat = relu(h1 @ m2w.T + m2b)
  gemm_tn<true, true><<<dim3(128, 4), 256, 0, stream>>>(
      h1, 256, m2w, 256, m2b, xfeat, 256, 0, 256, 256);

  // arc head: head = xfeat @ aw.T + ab
  gemm_tn<true, false><<<dim3(128, 4), 256, 0, stream>>>(
      xfeat, 256, aw, 256, ab, head, 256, 0, 256, 256);

  // rel projections (merged)
  rel_gemm<<<dim3(128, 2), 256, 0, stream>>>(head, xfeat, rw, rb, relh, reld);

  fused_scores<<<512 + (int)NT, 256, 0, stream>>>(
      head, xfeat, relh, reld, out, out + (size_t)Bv * Sv * Sv);
}